// Round 2
// baseline (2424.930 us; speedup 1.0000x reference)
//
#include <hip/hip_runtime.h>

typedef unsigned short u16;
typedef unsigned int u32;

typedef __attribute__((ext_vector_type(8))) __bf16 bf16x8;
typedef __attribute__((ext_vector_type(4))) float f32x4;

__device__ __forceinline__ float bf2f(u16 u) {
    u32 t = ((u32)u) << 16;
    float f;
    __builtin_memcpy(&f, &t, 4);
    return f;
}
__device__ __forceinline__ u16 f2bf(float f) {
    u32 u;
    __builtin_memcpy(&u, &f, 4);
    u32 r = (u + 0x7fffu + ((u >> 16) & 1u)) >> 16;
    return (u16)r;
}
__device__ __forceinline__ float tanh_fast(float x) {
    float xc = fminf(fmaxf(x, -15.f), 15.f);
    float e = __expf(2.f * xc);
    return (e - 1.f) / (e + 1.f);
}

// ---------------------------------------------------------------------------
// Generic 128x128-tile bf16 MFMA GEMM:  C[m,n] (+)= sum_t sum_k A_t[m,k]*W_t[n,k]
// A layout: [spatial][Bc][ldA] bf16 (k-contiguous rows). W layout: [T][N][ldW].
// For convs (T==9): m-tile sits at one spatial position; shift t=(kh,kw) offsets
// the spatial index; invalid shifts skipped (== zero padding). Shift-validity is
// block-uniform (whole 128-row tile sits at one spatial position since Bc%128==0).
// EPI 0: out = relu(acc*epiA[n] + epiB[n]) ; EPI 1: out = tanh(acc + epiB[n]).
// Output bf16 [spatial][Bc][ldO].
// ---------------------------------------------------------------------------
template <int EPI>
__global__ __launch_bounds__(256) void gemm_bt(
    const u16* __restrict__ A, const u16* __restrict__ W, u16* __restrict__ O,
    const float* __restrict__ epiA, const float* __restrict__ epiB,
    int Kin, int N, int T, int Himg, int Wimg,
    int ldA, int ldW, int ldO,
    long long Az, long long Wz, long long Oz, int epiZ,
    int Bc, int bshift)
{
    __shared__ __align__(16) u16 lsA[4096];
    __shared__ __align__(16) u16 lsW[4096];

    const int tid = threadIdx.x;
    const int z = blockIdx.z;
    A += (long long)z * Az;
    W += (long long)z * Wz;
    O += (long long)z * Oz;
    epiB += (long long)z * epiZ;

    const int m0 = blockIdx.x * 128;
    const int n0 = blockIdx.y * 128;
    const int s = m0 >> bshift;          // spatial index (0 for MLP)
    const int b0 = m0 & (Bc - 1);        // batch offset
    const int hh0 = s / Wimg, ww0 = s % Wimg;

    const int wave = tid >> 6;
    const int lane = tid & 63;
    const int wm = wave >> 1, wn = wave & 1;
    const int ln = lane & 15, qd = lane >> 4;

    const int r = tid >> 2;          // staging row (0..63)
    const int kq = (tid & 3) << 3;   // staging k offset (0,8,16,24)

    f32x4 acc[4][4];
#pragma unroll
    for (int i = 0; i < 4; ++i)
#pragma unroll
        for (int j = 0; j < 4; ++j)
            acc[i][j] = (f32x4){0.f, 0.f, 0.f, 0.f};

    for (int t = 0; t < T; ++t) {
        int sp;
        if (T == 9) {
            int hh = hh0 + t / 3 - 1;
            int ww = ww0 + t % 3 - 1;
            if (hh < 0 || hh >= Himg || ww < 0 || ww >= Wimg) continue;  // block-uniform
            sp = hh * Wimg + ww;
        } else {
            sp = s;
        }
        const u16* At = A + (long long)(sp * Bc + b0) * ldA;
        const u16* Wt = W + (long long)t * N * ldW + (long long)n0 * ldW;
        const u16* Ar0 = At + (long long)r * ldA + kq;
        const u16* Ar1 = At + (long long)(r + 64) * ldA + kq;
        const u16* Wr0 = Wt + (long long)r * ldW + kq;
        const u16* Wr1 = Wt + (long long)(r + 64) * ldW + kq;

        for (int k0 = 0; k0 < Kin; k0 += 32) {
            uint4 a0 = *(const uint4*)(Ar0 + k0);
            uint4 a1 = *(const uint4*)(Ar1 + k0);
            uint4 w0 = *(const uint4*)(Wr0 + k0);
            uint4 w1 = *(const uint4*)(Wr1 + k0);
            __syncthreads();
            // LDS elem offset tid*8 == (tid>>2)*32 + (tid&3)*8 == row*32 + kq
            *(uint4*)(lsA + tid * 8) = a0;
            *(uint4*)(lsA + 2048 + tid * 8) = a1;
            *(uint4*)(lsW + tid * 8) = w0;
            *(uint4*)(lsW + 2048 + tid * 8) = w1;
            __syncthreads();

            bf16x8 af[4], bfr[4];
#pragma unroll
            for (int f = 0; f < 4; ++f)
                af[f] = *(const bf16x8*)&lsA[(wm * 64 + f * 16 + ln) * 32 + qd * 8];
#pragma unroll
            for (int f = 0; f < 4; ++f)
                bfr[f] = *(const bf16x8*)&lsW[(wn * 64 + f * 16 + ln) * 32 + qd * 8];
#pragma unroll
            for (int i = 0; i < 4; ++i)
#pragma unroll
                for (int j = 0; j < 4; ++j)
                    acc[i][j] = __builtin_amdgcn_mfma_f32_16x16x32_bf16(
                        af[i], bfr[j], acc[i][j], 0, 0, 0);
        }
    }

#pragma unroll
    for (int j = 0; j < 4; ++j) {
        const int n = n0 + wn * 64 + j * 16 + ln;
        const float sh = epiB[n];
        float sc = 1.f;
        if (EPI == 0) sc = epiA[n];
#pragma unroll
        for (int i = 0; i < 4; ++i) {
            const int mrow = wm * 64 + i * 16 + qd * 4;
#pragma unroll
            for (int rr = 0; rr < 4; ++rr) {
                float v = acc[i][j][rr];
                if (EPI == 0) v = fmaxf(v * sc + sh, 0.f);
                else          v = tanh_fast(v + sh);
                O[(long long)(m0 + mrow + rr) * ldO + n] = f2bf(v);
            }
        }
    }
}

// ---------------------------------------------------------------------------
// x chunk [Bc,3,20,20] fp32 -> xt [400][Bc][3] bf16
// ---------------------------------------------------------------------------
__global__ __launch_bounds__(256) void transpose_x(
    const float* __restrict__ x, u16* __restrict__ xt, int Bc, int bshift)
{
    const int t = blockIdx.x * 256 + threadIdx.x;
    if (t >= 400 * Bc) return;
    const int s = t >> bshift;          // 0..399
    const int b = t & (Bc - 1);
    const float v0 = x[((long long)b * 3 + 0) * 400 + s];
    const float v1 = x[((long long)b * 3 + 1) * 400 + s];
    const float v2 = x[((long long)b * 3 + 2) * 400 + s];
    u16* o = xt + ((long long)s * Bc + b) * 3;
    o[0] = f2bf(v0); o[1] = f2bf(v1); o[2] = f2bf(v2);
}

// ---------------------------------------------------------------------------
// Fused conv1(3x3,p1)+BN+ReLU+maxpool(3,2,1): xt[400][Bc][3] -> p1[100][Bc][64]
// ---------------------------------------------------------------------------
__global__ __launch_bounds__(256) void conv1_pool1(
    const u16* __restrict__ xt, const float* __restrict__ W1,
    const float* __restrict__ bnA, const float* __restrict__ bnB,
    u16* __restrict__ p1, int Bc, int bshift)
{
    const int t = blockIdx.x * 256 + threadIdx.x;
    if (t >= 100 * Bc) return;
    const int so = t >> bshift;                // pooled spatial 0..99
    const int b = t & (Bc - 1);
    const int ho = so / 10, wo = so % 10;

    float px[5][5][3];                         // input patch rows 2ho-2..2ho+2
#pragma unroll
    for (int rI = 0; rI < 5; ++rI) {
        const int hr = 2 * ho - 2 + rI;
#pragma unroll
        for (int c = 0; c < 5; ++c) {
            const int wc = 2 * wo - 2 + c;
            if (hr >= 0 && hr < 20 && wc >= 0 && wc < 20) {
                const u16* q = xt + ((long long)(hr * 20 + wc) * Bc + b) * 3;
                px[rI][c][0] = bf2f(q[0]);
                px[rI][c][1] = bf2f(q[1]);
                px[rI][c][2] = bf2f(q[2]);
            } else {
                px[rI][c][0] = 0.f; px[rI][c][1] = 0.f; px[rI][c][2] = 0.f;
            }
        }
    }

    u16* outp = p1 + ((long long)so * Bc + b) * 64;

    for (int c8 = 0; c8 < 8; ++c8) {
        u32 packed[4];
#pragma unroll
        for (int uu = 0; uu < 8; ++uu) {
            const int co = c8 * 8 + uu;
            float wv[27];
#pragma unroll
            for (int q = 0; q < 27; ++q) wv[q] = W1[co * 27 + q];  // [ci][kh][kw]
            float best = -3e38f;
#pragma unroll
            for (int ph = 0; ph < 3; ++ph) {
                const int hwin = 2 * ho - 1 + ph;
                if (hwin < 0 || hwin >= 20) continue;    // pool pad = -inf
#pragma unroll
                for (int pw = 0; pw < 3; ++pw) {
                    const int wwin = 2 * wo - 1 + pw;
                    if (wwin < 0 || wwin >= 20) continue;
                    float sacc = 0.f;
#pragma unroll
                    for (int kh = 0; kh < 3; ++kh)
#pragma unroll
                        for (int kw = 0; kw < 3; ++kw)
#pragma unroll
                            for (int ci = 0; ci < 3; ++ci)
                                sacc += wv[ci * 9 + kh * 3 + kw] *
                                        px[ph + kh][pw + kw][ci];
                    best = fmaxf(best, sacc * bnA[co] + bnB[co]);  // bnA>0: affine commutes with max
                }
            }
            best = fmaxf(best, 0.f);  // relu commutes with max
            const u16 hv = f2bf(best);
            if (uu & 1) packed[uu >> 1] |= ((u32)hv) << 16;
            else        packed[uu >> 1] = (u32)hv;
        }
        uint4 st;
        st.x = packed[0]; st.y = packed[1]; st.z = packed[2]; st.w = packed[3];
        *(uint4*)(outp + c8 * 8) = st;
    }
}

// ---------------------------------------------------------------------------
// pool2: a2[100][Bc][128] -> p2[25][Bc][128]  (values already relu'd, >= 0)
// ---------------------------------------------------------------------------
__global__ __launch_bounds__(256) void pool2_k(
    const u16* __restrict__ a2, u16* __restrict__ p2, int Bc)
{
    const int t = blockIdx.x * 256 + threadIdx.x;  // Bc*16 threads
    const int cc = t & 15;
    const int b = t >> 4;
    if (b >= Bc) return;
    const int so = blockIdx.y;
    const int ho = so / 5, wo = so % 5;
    float best[8];
#pragma unroll
    for (int e = 0; e < 8; ++e) best[e] = 0.f;     // inputs >= 0
    for (int ph = 0; ph < 3; ++ph) {
        const int hh = 2 * ho - 1 + ph;
        if (hh < 0 || hh >= 10) continue;
        for (int pw = 0; pw < 3; ++pw) {
            const int ww = 2 * wo - 1 + pw;
            if (ww < 0 || ww >= 10) continue;
            const uint4 u = *(const uint4*)(a2 + ((long long)(hh * 10 + ww) * Bc + b) * 128 + cc * 8);
            const u32 uw[4] = {u.x, u.y, u.z, u.w};
#pragma unroll
            for (int e = 0; e < 4; ++e) {
                best[2 * e]     = fmaxf(best[2 * e],     bf2f((u16)(uw[e] & 0xffff)));
                best[2 * e + 1] = fmaxf(best[2 * e + 1], bf2f((u16)(uw[e] >> 16)));
            }
        }
    }
    u32 pk[4];
#pragma unroll
    for (int e = 0; e < 4; ++e)
        pk[e] = (u32)f2bf(best[2 * e]) | (((u32)f2bf(best[2 * e + 1])) << 16);
    uint4 st;
    st.x = pk[0]; st.y = pk[1]; st.z = pk[2]; st.w = pk[3];
    *(uint4*)(p2 + ((long long)so * Bc + b) * 128 + cc * 8) = st;
}

// ---------------------------------------------------------------------------
// Head: logits(600->10)+softmax from h[n][Bc][640] bf16.
// STAGE 1 -> preds bf16 [25][Bc][10]; STAGE 2 -> d_out[81920 + (n*8192+gb)*10] fp32.
// ---------------------------------------------------------------------------
template <int STAGE>
__global__ __launch_bounds__(256) void logits_softmax(
    const u16* __restrict__ h, const float* __restrict__ Wb, const float* __restrict__ bb,
    u16* __restrict__ preds, float* __restrict__ dout, int Bc, int bshift, int gbase)
{
    const int g = blockIdx.x * 256 + threadIdx.x;
    if (g >= 25 * Bc) return;
    const int n = g >> bshift;
    const int b = g & (Bc - 1);
    const u16* hr = h + (long long)g * 640;
    const float* Wn = Wb + n * 6000;
    float acc[10];
#pragma unroll
    for (int j = 0; j < 10; ++j) acc[j] = bb[n * 10 + j];
    for (int c0 = 0; c0 < 600; c0 += 8) {
        const uint4 u = *(const uint4*)(hr + c0);
        const u32 uw[4] = {u.x, u.y, u.z, u.w};
        float hv[8];
#pragma unroll
        for (int e = 0; e < 4; ++e) {
            hv[2 * e]     = bf2f((u16)(uw[e] & 0xffff));
            hv[2 * e + 1] = bf2f((u16)(uw[e] >> 16));
        }
#pragma unroll
        for (int e = 0; e < 8; ++e)
#pragma unroll
            for (int j = 0; j < 10; ++j)
                acc[j] += hv[e] * Wn[(c0 + e) * 10 + j];
    }
    float mx = acc[0];
#pragma unroll
    for (int j = 1; j < 10; ++j) mx = fmaxf(mx, acc[j]);
    float p[10], ssum = 0.f;
#pragma unroll
    for (int j = 0; j < 10; ++j) { p[j] = __expf(acc[j] - mx); ssum += p[j]; }
    const float inv = 1.f / ssum;
    if (STAGE == 1) {
        u16* o = preds + (long long)g * 10;
#pragma unroll
        for (int j = 0; j < 10; ++j) o[j] = f2bf(p[j] * inv);
    } else {
        float* o = dout + 81920 + ((long long)n * 8192 + gbase + b) * 10;
#pragma unroll
        for (int j = 0; j < 10; ++j) o[j] = p[j] * inv;
    }
}

// ---------------------------------------------------------------------------
// Stage-2 input assembly: A2[n][b][0:80]=masked neighbor preds (slot-ordered),
// [80:336]=feats, [336:352]=0.
// ---------------------------------------------------------------------------
__device__ __forceinline__ void neighbors5x5(int i, int* nb) {
    const int w = 5, size = 25;
    int cnt = 0;
    if (i - w >= 0) nb[cnt++] = i - w;
    if (i % w != 0) nb[cnt++] = i - 1;
    if ((i + 1) % w != 0) nb[cnt++] = i + 1;
    if (i + w < size) nb[cnt++] = i + w;
    if (i - w - 1 >= 0 && i % w != 0) nb[cnt++] = i - w - 1;
    if (i - w + 1 >= 0 && (i + 1) % w != 0) nb[cnt++] = i - w + 1;
    if (i + w - 1 < size && i % w != 0) nb[cnt++] = i + w - 1;
    if (i + w + 1 < size && (i + 1) % w != 0) nb[cnt++] = i + w + 1;
    for (; cnt < 8; ++cnt) nb[cnt] = -1;
}

__global__ __launch_bounds__(256) void gather_nb(
    const u16* __restrict__ preds, const u16* __restrict__ feats, u16* __restrict__ A2,
    int Bc, int bshift)
{
    const int g = blockIdx.x * 256 + threadIdx.x;  // n*Bc+b
    if (g >= 25 * Bc) return;
    const int n = g >> bshift;
    const int b = g & (Bc - 1);
    int nb[8];
    neighbors5x5(n, nb);
    u16* dst = A2 + (long long)g * 352;
#pragma unroll
    for (int j = 0; j < 8; ++j) {
        u32* d32 = (u32*)(dst + j * 10);
        if (nb[j] >= 0) {
            const u32* s32 = (const u32*)(preds + ((long long)nb[j] * Bc + b) * 10);
#pragma unroll
            for (int q = 0; q < 5; ++q) d32[q] = s32[q];
        } else {
#pragma unroll
            for (int q = 0; q < 5; ++q) d32[q] = 0u;
        }
    }
    const uint4* fs = (const uint4*)(feats + (long long)g * 256);
    uint4* fd = (uint4*)(dst + 80);
#pragma unroll
    for (int q = 0; q < 32; ++q) fd[q] = fs[q];
    uint4 z;
    z.x = 0u; z.y = 0u; z.z = 0u; z.w = 0u;
    *(uint4*)(dst + 336) = z;
    *(uint4*)(dst + 344) = z;
}

// ---------------------------------------------------------------------------
// mean over nodes: d_out[0:81920] = mean_n second[n]  (full batch, run once)
// ---------------------------------------------------------------------------
__global__ __launch_bounds__(256) void mean_k(float* __restrict__ dout)
{
    const int t = blockIdx.x * 256 + threadIdx.x;  // 0..81919
    float s = 0.f;
#pragma unroll
    for (int n = 0; n < 25; ++n) s += dout[81920 + n * 81920 + t];
    dout[t] = s * 0.04f;
}

// ---------------------------------------------------------------------------
// Weight/param prep kernels (small; rerun every launch, once — not per chunk)
// ---------------------------------------------------------------------------
__global__ void prep_bn_all(
    const float* b1, const float* g1, const float* be1, const float* m1, const float* v1,
    const float* b2, const float* g2, const float* be2, const float* m2, const float* v2,
    const float* b3, const float* g3, const float* be3, const float* m3, const float* v3,
    const float* b4, const float* g4, const float* be4, const float* m4, const float* v4,
    float* bnA, float* bnB)
{
    const int t = blockIdx.x * 256 + threadIdx.x;
    if (t >= 704) return;
    const float *bp, *gp, *bep, *mp, *vp;
    int idx;
    if (t < 64)       { bp=b1; gp=g1; bep=be1; mp=m1; vp=v1; idx=t; }
    else if (t < 192) { bp=b2; gp=g2; bep=be2; mp=m2; vp=v2; idx=t-64; }
    else if (t < 448) { bp=b3; gp=g3; bep=be3; mp=m3; vp=v3; idx=t-192; }
    else              { bp=b4; gp=g4; bep=be4; mp=m4; vp=v4; idx=t-448; }
    const float A = gp[idx] * rsqrtf(vp[idx] + 1e-5f);
    bnA[t] = A;
    bnB[t] = (bp[idx] - mp[idx]) * A + bep[idx];
}

// W [Co][Ci][3][3] fp32 -> Wt [9][Co][Ci] bf16
__global__ void prep_convw(const float* __restrict__ W, u16* __restrict__ Wt, int Co, int Ci)
{
    const int t = blockIdx.x * 256 + threadIdx.x;
    const int tot = 9 * Co * Ci;
    if (t >= tot) return;
    const int sh = t / (Co * Ci);
    const int rem = t % (Co * Ci);
    const int co = rem / Ci, ci = rem % Ci;
    Wt[t] = f2bf(W[(long long)(co * Ci + ci) * 9 + sh]);
}

// Wa [25][336][600] fp32 -> Wat [25][640][352] bf16 (transposed, zero-padded)
__global__ void prep_wat(const float* __restrict__ Wa, u16* __restrict__ Wat)
{
    const int t = blockIdx.x * 256 + threadIdx.x;
    if (t >= 25 * 640 * 352) return;
    const int n = t / (640 * 352);
    const int rem = t % (640 * 352);
    const int hcol = rem / 352;
    const int k = rem % 352;
    float v = 0.f;
    if (hcol < 600 && k < 336) v = Wa[((long long)n * 336 + k) * 600 + hcol];
    Wat[t] = f2bf(v);
}

// ba [25][600] -> ba_pad [25][640] fp32
__global__ void prep_ba(const float* __restrict__ ba, float* __restrict__ bap)
{
    const int t = blockIdx.x * 256 + threadIdx.x;
    if (t >= 25 * 640) return;
    const int n = t / 640, hcol = t % 640;
    bap[t] = (hcol < 600) ? ba[n * 600 + hcol] : 0.f;
}

// ---------------------------------------------------------------------------
extern "C" void kernel_launch(void* const* d_in, const int* in_sizes, int n_in,
                              void* d_out, int out_size, void* d_ws, size_t ws_size,
                              hipStream_t stream)
{
    (void)in_sizes; (void)n_in; (void)out_size;

    const float* x  = (const float*)d_in[0];
    const float* W1 = (const float*)d_in[1];
    const float* b1 = (const float*)d_in[2];
    const float* g1 = (const float*)d_in[3];
    const float* be1= (const float*)d_in[4];
    const float* m1 = (const float*)d_in[5];
    const float* v1 = (const float*)d_in[6];
    const float* W2 = (const float*)d_in[7];
    const float* b2 = (const float*)d_in[8];
    const float* g2 = (const float*)d_in[9];
    const float* be2= (const float*)d_in[10];
    const float* m2 = (const float*)d_in[11];
    const float* v2 = (const float*)d_in[12];
    const float* W3 = (const float*)d_in[13];
    const float* b3 = (const float*)d_in[14];
    const float* g3 = (const float*)d_in[15];
    const float* be3= (const float*)d_in[16];
    const float* v3_= (const float*)d_in[18];
    const float* m3 = (const float*)d_in[17];
    const float* W4 = (const float*)d_in[19];
    const float* b4 = (const float*)d_in[20];
    const float* g4 = (const float*)d_in[21];
    const float* be4= (const float*)d_in[22];
    const float* m4 = (const float*)d_in[23];
    const float* v4 = (const float*)d_in[24];
    const float* Wa = (const float*)d_in[25];
    const float* ba = (const float*)d_in[26];
    const float* Wb = (const float*)d_in[27];
    const float* bb = (const float*)d_in[28];
    float* dout = (float*)d_out;

    // ---- choose batch-chunk size Bc to fit ws_size (deterministic) ----
    auto al = [](long long v) { return (v + 255LL) & ~255LL; };
    const long long fixedB = al(147456) + al(589824) + al(1179648) +
                             al(11264000) + al(64000) + al(2816) + al(2816);
    int Bc = 128;
    for (int cand = 2048; cand >= 128; cand >>= 1) {
        long long need = fixedB + 2 * al(12800LL * cand) + al(17600LL * cand) +
                         al(32000LL * cand) + al(6400LL * cand) + al(500LL * cand);
        if (need <= (long long)ws_size) { Bc = cand; break; }
    }
    const int bshift = __builtin_ctz((unsigned)Bc);
    const int C = 8192 / Bc;

    // ---- workspace layout ----
    char* wsp = (char*)d_ws;
    long long off = 0;
    auto alloc = [&](long long bytes) { long long o = off; off += al(bytes); return o; };
    u16* Wt2  = (u16*)(wsp + alloc(147456));
    u16* Wt3  = (u16*)(wsp + alloc(589824));
    u16* Wt4  = (u16*)(wsp + alloc(1179648));
    u16* Wat  = (u16*)(wsp + alloc(11264000));
    float* bap = (float*)(wsp + alloc(64000));
    float* bnA = (float*)(wsp + alloc(2816));
    float* bnB = (float*)(wsp + alloc(2816));
    const long long oA4 = alloc(12800LL * Bc);   // a4 (feats), lives across stage 1+2
    const long long oR0 = alloc(12800LL * Bc);   // xt -> a3
    const long long oR1 = alloc(17600LL * Bc);   // p1 -> A2
    const long long oR2 = alloc(32000LL * Bc);   // a2 -> h
    const long long oR3 = alloc(6400LL * Bc);    // p2
    const long long oPr = alloc(500LL * Bc);     // preds
    u16* a4   = (u16*)(wsp + oA4);
    u16* xt   = (u16*)(wsp + oR0);
    u16* a3   = (u16*)(wsp + oR0);
    u16* p1   = (u16*)(wsp + oR1);
    u16* A2   = (u16*)(wsp + oR1);
    u16* a2   = (u16*)(wsp + oR2);
    u16* hbuf = (u16*)(wsp + oR2);
    u16* p2   = (u16*)(wsp + oR3);
    u16* preds= (u16*)(wsp + oPr);

    // ---- prep (once) ----
    prep_bn_all<<<dim3(3), 256, 0, stream>>>(b1,g1,be1,m1,v1, b2,g2,be2,m2,v2,
                                             b3,g3,be3,m3,v3_, b4,g4,be4,m4,v4, bnA, bnB);
    prep_convw<<<dim3(288),  256, 0, stream>>>(W2, Wt2, 128, 64);
    prep_convw<<<dim3(1152), 256, 0, stream>>>(W3, Wt3, 256, 128);
    prep_convw<<<dim3(2304), 256, 0, stream>>>(W4, Wt4, 256, 256);
    prep_wat<<<dim3(22000), 256, 0, stream>>>(Wa, Wat);
    prep_ba<<<dim3(63), 256, 0, stream>>>(ba, bap);

    // ---- batch chunks ----
    for (int c = 0; c < C; ++c) {
        const float* xc = x + (long long)c * Bc * 1200;

        transpose_x<<<dim3((400 * Bc + 255) / 256), 256, 0, stream>>>(xc, xt, Bc, bshift);
        conv1_pool1<<<dim3((100 * Bc + 255) / 256), 256, 0, stream>>>(xt, W1, bnA, bnB, p1, Bc, bshift);
        gemm_bt<0><<<dim3(100 * Bc / 128, 1), 256, 0, stream>>>(p1, Wt2, a2, bnA + 64, bnB + 64,
            64, 128, 9, 10, 10, 64, 64, 128, 0LL, 0LL, 0LL, 0, Bc, bshift);
        pool2_k<<<dim3(Bc / 16, 25), 256, 0, stream>>>(a2, p2, Bc);
        gemm_bt<0><<<dim3(25 * Bc / 128, 2), 256, 0, stream>>>(p2, Wt3, a3, bnA + 192, bnB + 192,
            128, 256, 9, 5, 5, 128, 128, 256, 0LL, 0LL, 0LL, 0, Bc, bshift);
        gemm_bt<0><<<dim3(25 * Bc / 128, 2), 256, 0, stream>>>(a3, Wt4, a4, bnA + 448, bnB + 448,
            256, 256, 9, 5, 5, 256, 256, 256, 0LL, 0LL, 0LL, 0, Bc, bshift);

        // stage 1 MLP: zeros||feats -> only k-rows [80:336) of Wa matter
        gemm_bt<1><<<dim3(Bc / 128, 5, 25), 256, 0, stream>>>(a4, Wat + 80, hbuf, nullptr, bap,
            256, 640, 1, 1, 1, 256, 352, 640,
            (long long)Bc * 256, 640LL * 352, (long long)Bc * 640, 640, Bc, bshift);
        logits_softmax<1><<<dim3((25 * Bc + 255) / 256), 256, 0, stream>>>(
            hbuf, Wb, bb, preds, nullptr, Bc, bshift, 0);

        // stage 2
        gather_nb<<<dim3((25 * Bc + 255) / 256), 256, 0, stream>>>(preds, a4, A2, Bc, bshift);
        gemm_bt<1><<<dim3(Bc / 128, 5, 25), 256, 0, stream>>>(A2, Wat, hbuf, nullptr, bap,
            352, 640, 1, 1, 1, 352, 352, 640,
            (long long)Bc * 352, 640LL * 352, (long long)Bc * 640, 640, Bc, bshift);
        logits_softmax<2><<<dim3((25 * Bc + 255) / 256), 256, 0, stream>>>(
            hbuf, Wb, bb, nullptr, dout, Bc, bshift, c * Bc);
    }

    mean_k<<<dim3(320), 256, 0, stream>>>(dout);
}